// Round 3
// baseline (171.225 us; speedup 1.0000x reference)
//
#include <hip/hip_runtime.h>
#include <hip/hip_bf16.h>

// Problem constants (B=1). All inputs/outputs are float32 (per reference).
#define HH   96
#define WW   96
#define NPIX 9216          // 96*96
#define CH   128
#define NH   8
#define HD   16
#define KS   8

// unpack uint4 = 8 bf16 (little-endian pairs) -> 8 fp32
__device__ __forceinline__ void u4_to_f8(uint4 u, float* f) {
    f[0] = __uint_as_float(u.x << 16); f[1] = __uint_as_float(u.x & 0xffff0000u);
    f[2] = __uint_as_float(u.y << 16); f[3] = __uint_as_float(u.y & 0xffff0000u);
    f[4] = __uint_as_float(u.z << 16); f[5] = __uint_as_float(u.z & 0xffff0000u);
    f[6] = __uint_as_float(u.w << 16); f[7] = __uint_as_float(u.w & 0xffff0000u);
}

// ---------------------------------------------------------------------------
// K1: depthwise 3x3 conv (feature_group_count=128 -> out ch o uses in ch o/3)
// fp32 inputs -> q,k,v stored bf16, layout [3][NPIX][CH] (7.08 MB workspace)
// thread = pix*128 + c (lanes consecutive in c -> coalesced qkv stores;
// x reads are channel-strided but x (4.7 MB) is L2-resident with 27x reuse)
// ---------------------------------------------------------------------------
__global__ __launch_bounds__(256) void conv_qkv_kernel(
    const float* __restrict__ x,      // [128][96][96] fp32
    const float* __restrict__ w,      // [384][1][3][3] fp32
    const float* __restrict__ bias,   // [384] fp32
    __hip_bfloat16* __restrict__ qkv) // [3][NPIX][CH] bf16
{
    const int idx = blockIdx.x * 256 + threadIdx.x;
    const int c   = idx & (CH - 1);
    const int pix = idx >> 7;
    const int i   = pix / WW;
    const int j   = pix % WW;

    #pragma unroll
    for (int t = 0; t < 3; ++t) {
        const int o = t * CH + c;          // conv output channel in [0,384)
        const int g = o / 3;               // input channel (XLA grouped-conv mapping)
        float acc = bias[o];
        const float* xg = x + g * NPIX;
        const float* wo = w + o * 9;
        #pragma unroll
        for (int kh = 0; kh < 3; ++kh) {
            const int ii = i + kh - 1;
            if (ii < 0 || ii >= HH) continue;
            #pragma unroll
            for (int kw = 0; kw < 3; ++kw) {
                const int jj = j + kw - 1;
                if (jj < 0 || jj >= WW) continue;
                acc += xg[ii * WW + jj] * wo[kh * 3 + kw];
            }
        }
        qkv[t * (NPIX * CH) + pix * CH + c] = __float2bfloat16(acc);
    }
}

// ---------------------------------------------------------------------------
// K2: fused neighborhood attention + 1x1 projection.
// Block = 256 threads = 32 consecutive pixels x 8 heads.
// Window rows/cols: 2*(clamp(i/2-3,0,40)+p), p=0..7  (closed form of
// axis_indices for KS=8, stride=2, dil=2: center even -> r=0, Lsub=48).
// Attention output fp32 in LDS a_t[c][px]; proj_w (fp32) staged transposed
// as bf16 in LDS; projection register-blocked 4px x 4o; fp32 output.
// ---------------------------------------------------------------------------
__global__ __launch_bounds__(256) void attn_proj_kernel(
    const __hip_bfloat16* __restrict__ qkv,    // [3][NPIX][CH] bf16
    const float* __restrict__ pw,              // [128][128] fp32 ([o][c])
    const float* __restrict__ pb,              // [128] fp32
    float* __restrict__ out)                   // [128][NPIX] fp32
{
    __shared__ float          a_t[CH * 32];    // [c][px], stride 32 (16 KB)
    __shared__ __hip_bfloat16 wT[CH * CH];     // [c][o]            (32 KB)

    const int t = threadIdx.x;

    // ---- stage proj_w transposed: wT[c][o] = bf16(pw[o][c]) ----
    {
        const int o  = t >> 1;
        const int c0 = (t & 1) * 64;
        #pragma unroll
        for (int k4 = 0; k4 < 16; ++k4) {
            const float4 f = *(const float4*)(pw + o * CH + c0 + k4 * 4);
            wT[(c0 + k4 * 4 + 0) * CH + o] = __float2bfloat16(f.x);
            wT[(c0 + k4 * 4 + 1) * CH + o] = __float2bfloat16(f.y);
            wT[(c0 + k4 * 4 + 2) * CH + o] = __float2bfloat16(f.z);
            wT[(c0 + k4 * 4 + 3) * CH + o] = __float2bfloat16(f.w);
        }
    }

    // ---- attention: thread = (px, head) ----
    const int px  = t & 31;
    const int n   = t >> 5;
    const int pix = blockIdx.x * 32 + px;
    const int i   = pix / WW;
    const int j   = pix % WW;
    const int rs  = 2 * min(max(i / 2 - 3, 0), 40);
    const int cs  = 2 * min(max(j / 2 - 3, 0), 40);

    const __hip_bfloat16* qp = qkv + pix * CH + n * HD;
    const __hip_bfloat16* kb = qkv + NPIX * CH + n * HD;
    const __hip_bfloat16* vb = qkv + 2 * (NPIX * CH) + n * HD;

    float qr[HD];
    {
        uint4 u0 = *(const uint4*)qp;
        uint4 u1 = *(const uint4*)(qp + 8);
        u4_to_f8(u0, qr); u4_to_f8(u1, qr + 8);
        #pragma unroll
        for (int d = 0; d < HD; ++d) qr[d] *= 0.25f;   // scale = HD^-0.5
    }

    float logits[64];
    float m = -1e30f;
    #pragma unroll
    for (int p = 0; p < KS; ++p) {
        const int r = rs + 2 * p;
        #pragma unroll
        for (int q = 0; q < KS; ++q) {
            const int cc = cs + 2 * q;
            const __hip_bfloat16* kp = kb + (r * WW + cc) * CH;
            float kf[HD];
            uint4 u0 = *(const uint4*)kp;
            uint4 u1 = *(const uint4*)(kp + 8);
            u4_to_f8(u0, kf); u4_to_f8(u1, kf + 8);
            float acc = 0.f;
            #pragma unroll
            for (int d = 0; d < HD; ++d) acc += qr[d] * kf[d];
            logits[p * KS + q] = acc;
            m = fmaxf(m, acc);
        }
    }

    float s = 0.f;
    #pragma unroll
    for (int e = 0; e < 64; ++e) { logits[e] = __expf(logits[e] - m); s += logits[e]; }
    const float inv = 1.f / s;

    float o[HD];
    #pragma unroll
    for (int d = 0; d < HD; ++d) o[d] = 0.f;
    #pragma unroll
    for (int p = 0; p < KS; ++p) {
        const int r = rs + 2 * p;
        #pragma unroll
        for (int q = 0; q < KS; ++q) {
            const int cc = cs + 2 * q;
            const __hip_bfloat16* vp = vb + (r * WW + cc) * CH;
            float vf[HD];
            uint4 u0 = *(const uint4*)vp;
            uint4 u1 = *(const uint4*)(vp + 8);
            u4_to_f8(u0, vf); u4_to_f8(u1, vf + 8);
            const float wgt = logits[p * KS + q];
            #pragma unroll
            for (int d = 0; d < HD; ++d) o[d] += wgt * vf[d];
        }
    }

    #pragma unroll
    for (int d = 0; d < HD; ++d)
        a_t[(n * HD + d) * 32 + px] = o[d] * inv;

    __syncthreads();

    // ---- projection: thread = (pq -> 4 px, og -> 4 o) ----
    const int pq  = t & 7;
    const int og  = t >> 3;
    const int px4 = pq * 4;
    const int o4  = og * 4;

    float acc[4][4];   // [pu][ou]
    #pragma unroll
    for (int ou = 0; ou < 4; ++ou) {
        const float b = pb[o4 + ou];
        #pragma unroll
        for (int pu = 0; pu < 4; ++pu) acc[pu][ou] = b;
    }

    for (int c = 0; c < CH; ++c) {
        const float4 a = *(const float4*)&a_t[c * 32 + px4];
        const uint2 uw = *(const uint2*)&wT[c * CH + o4];
        const float w0 = __uint_as_float(uw.x << 16);
        const float w1 = __uint_as_float(uw.x & 0xffff0000u);
        const float w2 = __uint_as_float(uw.y << 16);
        const float w3 = __uint_as_float(uw.y & 0xffff0000u);
        const float av[4] = {a.x, a.y, a.z, a.w};
        const float wv[4] = {w0, w1, w2, w3};
        #pragma unroll
        for (int pu = 0; pu < 4; ++pu)
            #pragma unroll
            for (int ou = 0; ou < 4; ++ou)
                acc[pu][ou] += av[pu] * wv[ou];
    }

    const int pix0 = blockIdx.x * 32;
    #pragma unroll
    for (int ou = 0; ou < 4; ++ou)
        #pragma unroll
        for (int pu = 0; pu < 4; ++pu)
            out[(o4 + ou) * NPIX + pix0 + px4 + pu] = acc[pu][ou];
}

// ---------------------------------------------------------------------------
extern "C" void kernel_launch(void* const* d_in, const int* in_sizes, int n_in,
                              void* d_out, int out_size, void* d_ws, size_t ws_size,
                              hipStream_t stream)
{
    const float* x      = (const float*)d_in[0];
    const float* qkv_w  = (const float*)d_in[1];
    const float* qkv_b  = (const float*)d_in[2];
    const float* proj_w = (const float*)d_in[3];
    const float* proj_b = (const float*)d_in[4];
    float* out = (float*)d_out;

    __hip_bfloat16* qkv = (__hip_bfloat16*)d_ws;   // [3][NPIX][CH] bf16, 7.08 MB

    conv_qkv_kernel<<<NPIX * CH / 256, 256, 0, stream>>>(x, qkv_w, qkv_b, qkv);
    attn_proj_kernel<<<NPIX / 32, 256, 0, stream>>>(qkv, proj_w, proj_b, out);
}

// Round 4
// 131.169 us; speedup vs baseline: 1.3054x; 1.3054x over previous
//
#include <hip/hip_runtime.h>
#include <hip/hip_bf16.h>

// Problem constants (B=1). All inputs/outputs are float32.
#define HH   96
#define WW   96
#define NPIX 9216          // 96*96
#define CH   128
#define NH   8
#define HD   16
#define KS   8

#define NPOS 120           // 8 window rows x 15 window cols staged per block
#define SEGPX 16           // pixels per attention block (one row segment)

__device__ __forceinline__ float bf2f(unsigned short h) {
    return __uint_as_float(((unsigned)h) << 16);
}
__device__ __forceinline__ unsigned short f2bf(float f) {
    __hip_bfloat16 b = __float2bfloat16(f);
    union { __hip_bfloat16 b; unsigned short u; } cv; cv.b = b; return cv.u;
}
// unpack uint4 = 8 bf16 -> 8 fp32
__device__ __forceinline__ void u4_to_f8(uint4 u, float* f) {
    f[0] = __uint_as_float(u.x << 16); f[1] = __uint_as_float(u.x & 0xffff0000u);
    f[2] = __uint_as_float(u.y << 16); f[3] = __uint_as_float(u.y & 0xffff0000u);
    f[4] = __uint_as_float(u.z << 16); f[5] = __uint_as_float(u.z & 0xffff0000u);
    f[6] = __uint_as_float(u.w << 16); f[7] = __uint_as_float(u.w & 0xffff0000u);
}

// ---------------------------------------------------------------------------
// K1: depthwise 3x3 conv, channel-major output [3][CH][NPIX] bf16.
// thread = 8 consecutive pixels of one input channel g; g wave-uniform
// (1152 chunks per channel, 1152 % 64 == 0) -> weights via scalar loads.
// All reads/writes coalesced. Zero-pad edges in registers.
// ---------------------------------------------------------------------------
__global__ __launch_bounds__(256) void conv_cm_kernel(
    const float* __restrict__ x,        // [128][96][96]
    const float* __restrict__ w,        // [384][1][3][3]
    const float* __restrict__ bias,     // [384]
    unsigned short* __restrict__ qkv_cm)// [3][CH][NPIX] bf16
{
    const int T     = blockIdx.x * 256 + threadIdx.x;   // < 147456
    const int g     = __builtin_amdgcn_readfirstlane(T / 1152); // wave-uniform
    const int chunk = T - g * 1152;
    const int row   = chunk / 12;
    const int j0    = (chunk - row * 12) * 8;

    const float* xg = x + g * NPIX;

    float xr[3][10];
    #pragma unroll
    for (int dr = 0; dr < 3; ++dr) {
        const int r = row + dr - 1;
        if (r >= 0 && r < HH) {
            #pragma unroll
            for (int m = 0; m < 10; ++m) {
                const int j = j0 + m - 1;
                xr[dr][m] = (j >= 0 && j < WW) ? xg[r * WW + j] : 0.f;
            }
        } else {
            #pragma unroll
            for (int m = 0; m < 10; ++m) xr[dr][m] = 0.f;
        }
    }

    #pragma unroll
    for (int dt = 0; dt < 3; ++dt) {
        const int o = 3 * g + dt;            // conv out-channel (group g)
        float w9[9];
        #pragma unroll
        for (int k = 0; k < 9; ++k) w9[k] = w[o * 9 + k];
        const float b = bias[o];

        union { uint4 u; unsigned short h[8]; } res;
        #pragma unroll
        for (int px = 0; px < 8; ++px) {
            float acc = b;
            #pragma unroll
            for (int kh = 0; kh < 3; ++kh)
                #pragma unroll
                for (int kw = 0; kw < 3; ++kw)
                    acc += xr[kh][px + kw] * w9[kh * 3 + kw];
            res.h[px] = f2bf(acc);
        }
        const int t = o >> 7, c = o & 127;   // qkv[t][c] = conv channel t*128+c
        *(uint4*)(qkv_cm + ((t * CH + c) * NPIX + row * WW + j0)) = res.u;
    }
}

// ---------------------------------------------------------------------------
// K2: transpose [3][CH][NPIX] -> [3][NPIX][CH] (bf16), 64x64 LDS tiles.
// Both global read and write are 16B coalesced.
// ---------------------------------------------------------------------------
__global__ __launch_bounds__(256) void transpose_kernel(
    const unsigned short* __restrict__ in,   // [3][CH][NPIX]
    unsigned short* __restrict__ out)        // [3][NPIX][CH]
{
    __shared__ unsigned short tile[64][65];

    const int t  = blockIdx.y;
    const int ct = blockIdx.x & 1;       // 2 channel tiles
    const int pt = blockIdx.x >> 1;      // 144 pixel tiles
    const int c0 = ct * 64, p0 = pt * 64;

    const unsigned short* ip = in  + t * CH * NPIX;
    unsigned short*       op = out + t * NPIX * CH;

    const int rl = threadIdx.x >> 3;     // 0..31
    const int pc = threadIdx.x & 7;      // 0..7

    #pragma unroll
    for (int pass = 0; pass < 2; ++pass) {
        const int r = pass * 32 + rl;    // channel row within tile
        union { uint4 u; unsigned short h[8]; } cv;
        cv.u = *(const uint4*)(ip + (c0 + r) * NPIX + p0 + pc * 8);
        #pragma unroll
        for (int e = 0; e < 8; ++e) tile[pc * 8 + e][r] = cv.h[e];
    }
    __syncthreads();
    #pragma unroll
    for (int pass = 0; pass < 2; ++pass) {
        const int pr = pass * 32 + rl;   // pixel row within tile
        union { uint4 u; unsigned short h[8]; } cv;
        #pragma unroll
        for (int e = 0; e < 8; ++e) cv.h[e] = tile[pr][pc * 8 + e];
        *(uint4*)(op + (p0 + pr) * CH + c0 + pc * 8) = cv.u;
    }
}

// ---------------------------------------------------------------------------
// K3: neighborhood attention with LDS-staged K/V windows.
// Block = 16 consecutive pixels (one row segment; rs uniform) x 8 heads
// = 128 threads. Window union = 8 rows x 15 cols = 120 positions, all
// in-bounds pixels. K,V staged bf16 with XOR swizzle ((pos&7)*32B) to
// break the 256B-stride bank alias. Output a_t[c][pix] fp32.
// ---------------------------------------------------------------------------
__global__ __launch_bounds__(128) void attn_kernel(
    const unsigned short* __restrict__ qkv_pm,  // [3][NPIX][CH] bf16
    float* __restrict__ a_t)                    // [CH][NPIX] fp32
{
    __shared__ unsigned short kvs[2][NPOS * CH];   // 61,440 B

    const int seg = blockIdx.x;                 // 0..575
    const int i   = seg / 6;                    // row (16 px per segment, 6/row)
    const int j0  = (seg - i * 6) * SEGPX;
    const int rs     = 2 * min(max(i / 2 - 3, 0), 40);
    const int cs_min = 2 * min(max(j0 / 2 - 3, 0), 40);

    const int tid = threadIdx.x;

    // ---- stage K and V (120 pos x 128 ch, 16B chunks) ----
    #pragma unroll
    for (int it = 0; it < 15; ++it) {
        const int c2  = it * 128 + tid;         // < 1920
        const int pos = c2 >> 4;
        const int och = (c2 & 15) * 8;
        const int p   = pos / 15;
        const int cc  = pos - p * 15;
        const int pixg = (rs + 2 * p) * WW + cs_min + 2 * cc;  // always < NPIX
        const int lidx = pos * CH + (och ^ ((pos & 7) << 4));
        *(uint4*)&kvs[0][lidx] = *(const uint4*)(qkv_pm + (NPIX + pixg) * CH + och);
        *(uint4*)&kvs[1][lidx] = *(const uint4*)(qkv_pm + (2 * NPIX + pixg) * CH + och);
    }
    __syncthreads();

    // ---- per-thread attention ----
    const int px  = tid & 15;
    const int n   = tid >> 4;
    const int pix = seg * SEGPX + px;
    const int j   = j0 + px;
    const int ci0 = (2 * min(max(j / 2 - 3, 0), 40) - cs_min) >> 1;   // 0..7

    float qr[HD];
    {
        const unsigned short* qp = qkv_pm + pix * CH + n * HD;
        uint4 u0 = *(const uint4*)qp;
        uint4 u1 = *(const uint4*)(qp + 8);
        u4_to_f8(u0, qr); u4_to_f8(u1, qr + 8);
        #pragma unroll
        for (int d = 0; d < HD; ++d) qr[d] *= 0.25f;   // HD^-0.5
    }

    float logits[64];
    float m = -1e30f;
    #pragma unroll
    for (int p = 0; p < KS; ++p) {
        #pragma unroll
        for (int q = 0; q < KS; ++q) {
            const int pos  = p * 15 + ci0 + q;
            const int lidx = pos * CH + (((n << 4) ^ ((pos & 7) << 4)));
            float kf[HD];
            uint4 u0 = *(const uint4*)&kvs[0][lidx];
            uint4 u1 = *(const uint4*)&kvs[0][lidx + 8];
            u4_to_f8(u0, kf); u4_to_f8(u1, kf + 8);
            float acc = 0.f;
            #pragma unroll
            for (int d = 0; d < HD; ++d) acc += qr[d] * kf[d];
            logits[p * KS + q] = acc;
            m = fmaxf(m, acc);
        }
    }

    float s = 0.f;
    #pragma unroll
    for (int e = 0; e < 64; ++e) { logits[e] = __expf(logits[e] - m); s += logits[e]; }
    const float inv = 1.f / s;

    float o[HD];
    #pragma unroll
    for (int d = 0; d < HD; ++d) o[d] = 0.f;
    #pragma unroll
    for (int p = 0; p < KS; ++p) {
        #pragma unroll
        for (int q = 0; q < KS; ++q) {
            const int pos  = p * 15 + ci0 + q;
            const int lidx = pos * CH + (((n << 4) ^ ((pos & 7) << 4)));
            float vf[HD];
            uint4 u0 = *(const uint4*)&kvs[1][lidx];
            uint4 u1 = *(const uint4*)&kvs[1][lidx + 8];
            u4_to_f8(u0, vf); u4_to_f8(u1, vf + 8);
            const float wgt = logits[p * KS + q];
            #pragma unroll
            for (int d = 0; d < HD; ++d) o[d] += wgt * vf[d];
        }
    }

    #pragma unroll
    for (int d = 0; d < HD; ++d)
        a_t[(n * HD + d) * NPIX + pix] = o[d] * inv;
}

// ---------------------------------------------------------------------------
// K4: 1x1 projection. thread = (o-group of 8, pixel); lanes over pix.
// o-group wave-uniform -> proj weights via scalar loads; a_t reads coalesced.
// ---------------------------------------------------------------------------
__global__ __launch_bounds__(256) void proj_kernel(
    const float* __restrict__ a_t,      // [CH][NPIX]
    const float* __restrict__ pw,       // [128][128] ([o][c])
    const float* __restrict__ pb,       // [128]
    float* __restrict__ out)            // [128][NPIX]
{
    const int idx = blockIdx.x * 256 + threadIdx.x;
    const int og  = __builtin_amdgcn_readfirstlane(idx / NPIX);  // 0..15
    const int pix = idx - og * NPIX;
    const int o0  = og * 8;

    float acc[8];
    #pragma unroll
    for (int u = 0; u < 8; ++u) acc[u] = pb[o0 + u];

    for (int c = 0; c < CH; ++c) {
        const float a = a_t[c * NPIX + pix];
        #pragma unroll
        for (int u = 0; u < 8; ++u) acc[u] += a * pw[(o0 + u) * CH + c];
    }

    #pragma unroll
    for (int u = 0; u < 8; ++u)
        out[(o0 + u) * NPIX + pix] = acc[u];
}

// ---------------------------------------------------------------------------
extern "C" void kernel_launch(void* const* d_in, const int* in_sizes, int n_in,
                              void* d_out, int out_size, void* d_ws, size_t ws_size,
                              hipStream_t stream)
{
    const float* x      = (const float*)d_in[0];
    const float* qkv_w  = (const float*)d_in[1];
    const float* qkv_b  = (const float*)d_in[2];
    const float* proj_w = (const float*)d_in[3];
    const float* proj_b = (const float*)d_in[4];
    float* out = (float*)d_out;

    unsigned short* qkv_cm = (unsigned short*)d_ws;          // [3][CH][NPIX] bf16
    unsigned short* qkv_pm = qkv_cm + 3 * CH * NPIX;         // [3][NPIX][CH] bf16
    float*          a_t    = (float*)d_ws;                   // aliases qkv_cm (dead after transpose)

    conv_cm_kernel <<<576, 256, 0, stream>>>(x, qkv_w, qkv_b, qkv_cm);
    transpose_kernel<<<dim3(288, 3), 256, 0, stream>>>(qkv_cm, qkv_pm);
    attn_kernel    <<<576, 128, 0, stream>>>(qkv_pm, a_t);
    proj_kernel    <<<576, 256, 0, stream>>>(a_t, proj_w, proj_b, out);
}